// Round 12
// baseline (171.217 us; speedup 1.0000x reference)
//
#include <hip/hip_runtime.h>
#include <hip/hip_fp16.h>
#include <math.h>

// Normalization_60095182406123
//
// Separable 4D Gaussian filter of x^2 over axes (freq, orient, y, x):
//   out[c,y,x] = sum g3[df] g3[do] g32[dy] g32[dx] * xsq[c+(df-1)*16+(do-1)*2, y+dy-16, x+dx-16]
// c = img*192 + freq*16 + orient*2 + phase (same flat layout in and out).
//
// Pass 1 (unchanged since R8): x^2 + orient(3) + freq(3) + blur_x(32) -> ws (fp16), ~42 us
// Pass 2 (R12): blur_y(32) fp16->fp32, dual accumulation with a 2-col x 8-out tile.
//   TOOLCHAIN LESSON (R9-R11): arrays >~16 floats in deep unrolls are NOT
//   register-promoted (VGPR stuck at 32-36 -> scratch-latency-bound). Keep
//   per-thread array state at <=16 floats with static indices only, no shifts.
//   Thread: 39 half2 row-loads (coalesced 256B/wave), FMA into a0[8],a1[8],
//   8 float2 stores. 2.4M threads for TLP.
//
// ws needs 768*224*224*2 = 77,070,336 bytes of d_ws.

#define SZW   224
#define PLANE (224*224)
#define PW    256          // floats per LDS row: 16 zero | 224 data | 15 zero | 1 spare

struct GaussArgs {
    float wx[32];   // 32-tap Gaussian (l=32, w=1), matches reference _gauss
    float w30;      // 3-tap edge   = c*exp(-0.5)
    float w31;      // 3-tap center = c
};

// within-row float4-group swizzle (involution, preserves 8-group blocks)
__device__ __forceinline__ int swz(int g) { return g ^ ((g >> 3) & 7); }

__global__ __launch_bounds__(512, 6) void pass1_kernel(const float* __restrict__ in,
                                                       __half* __restrict__ ws,
                                                       const GaussArgs ga)
{
    __shared__ float s2[48 * PW];   // 49,152 B

    const int tid   = threadIdx.x;
    const int y     = blockIdx.x;          // 0..223
    const int by    = blockIdx.y;          // 0..5
    const int phase = by & 1;
    const int fg    = by >> 1;             // freq group: output f in [4fg, 4fg+4)
    const int img   = blockIdx.z;          // 0..3

    const float w31 = ga.w31;
    const float w30 = ga.w30;

    // ---- step 1: load x^2 (x-padded), orient 3-tap conv in regs, to LDS ----
    if (tid < 384) {
        const int lf  = tid >> 6;          // 0..5
        const int xp4 = tid & 63;
        const int f   = 4*fg - 1 + lf;     // -1..12
        const int gsw = swz(xp4);
        float4 a[8];
        if (f >= 0 && f < 12 && xp4 >= 4 && xp4 < 60) {
            const int x0 = xp4*4 - 16;     // 0..220, 16B-aligned
            const float* base = in + (size_t)(img*192 + f*16 + phase)*PLANE + y*SZW + x0;
            #pragma unroll
            for (int o = 0; o < 8; ++o) {
                float4 v = *reinterpret_cast<const float4*>(base + o*2*PLANE);
                a[o] = make_float4(v.x*v.x, v.y*v.y, v.z*v.z, v.w*v.w);
            }
        } else {
            #pragma unroll
            for (int o = 0; o < 8; ++o) a[o] = make_float4(0.f,0.f,0.f,0.f);
        }
        #pragma unroll
        for (int o = 0; o < 8; ++o) {
            float4 l = (o > 0) ? a[o-1] : make_float4(0.f,0.f,0.f,0.f);
            float4 r = (o < 7) ? a[o+1] : make_float4(0.f,0.f,0.f,0.f);
            float4 b;
            b.x = fmaf(w31, a[o].x, w30*(l.x + r.x));
            b.y = fmaf(w31, a[o].y, w30*(l.y + r.y));
            b.z = fmaf(w31, a[o].z, w30*(l.z + r.z));
            b.w = fmaf(w31, a[o].w, w30*(l.w + r.w));
            *reinterpret_cast<float4*>(&s2[(lf*8 + o)*PW + gsw*4]) = b;
        }
    }
    __syncthreads();

    // ---- step 2: freq 3-tap conv in place ----
    {
        const int o   = tid >> 6;          // 0..7
        const int xp4 = tid & 63;
        const int gsw = swz(xp4);
        float4 a[6];
        #pragma unroll
        for (int lf = 0; lf < 6; ++lf)
            a[lf] = *reinterpret_cast<const float4*>(&s2[(lf*8 + o)*PW + gsw*4]);
        #pragma unroll
        for (int lf = 1; lf < 5; ++lf) {
            float4 b;
            b.x = fmaf(w31, a[lf].x, w30*(a[lf-1].x + a[lf+1].x));
            b.y = fmaf(w31, a[lf].y, w30*(a[lf-1].y + a[lf+1].y));
            b.z = fmaf(w31, a[lf].z, w30*(a[lf-1].z + a[lf+1].z));
            b.w = fmaf(w31, a[lf].w, w30*(a[lf-1].w + a[lf+1].w));
            *reinterpret_cast<float4*>(&s2[(lf*8 + o)*PW + gsw*4]) = b;
        }
    }
    __syncthreads();

    // ---- step 3: 32-tap blur along x, 16 outputs/thread, fp16 store ----
    if (tid < 448) {
        const int r  = tid / 14;           // 0..31
        const int xg = tid - r*14;         // 0..13
        const int lf = 1 + (r >> 3);
        const int o  = r & 7;
        const int fo16 = (4*fg + (r >> 3))*16 + o*2;
        const int x0 = xg * 16;            // output x base (0..208)
        const int rowb = (lf*8 + o)*PW;
        const int g0 = 4*xg;

        float acc[16];
        #pragma unroll
        for (int j = 0; j < 16; ++j) acc[j] = 0.f;

        #pragma unroll
        for (int t = 0; t < 12; ++t) {
            const float4 q = *reinterpret_cast<const float4*>(
                &s2[rowb + swz(g0 + t)*4]);
            #pragma unroll
            for (int e = 0; e < 4; ++e) {
                const int m = 4*t + e;     // window float index 0..47
                const float qv = (e==0)?q.x:(e==1)?q.y:(e==2)?q.z:q.w;
                const int jlo = (m - 31 > 0) ? (m - 31) : 0;
                const int jhi = (m < 15) ? m : 15;
                #pragma unroll
                for (int j = jlo; j <= jhi; ++j)
                    acc[j] = fmaf(ga.wx[m - j], qv, acc[j]);
            }
        }

        union { uint4 u4[2]; __half2 h2[8]; } pk;
        #pragma unroll
        for (int s = 0; s < 8; ++s)
            pk.h2[s] = __floats2half2_rn(acc[2*s], acc[2*s+1]);

        __half* op = ws + (size_t)(img*192 + phase)*PLANE + (size_t)y*SZW
                        + (size_t)fo16*PLANE + x0;
        *reinterpret_cast<uint4*>(op)     = pk.u4[0];
        *reinterpret_cast<uint4*>(op + 8) = pk.u4[1];
    }
}

// Pass 2: y-blur, dual accumulation. Thread = (ch, yt, cg): 8 output rows x 2 cols.
// Stream 39 rows as half2 loads; 16 static accumulators; 8 float2 stores.
// Unit order: cg fastest -> consecutive lanes load consecutive half2 (coalesced).
__global__ __launch_bounds__(256, 4) void pass2_kernel(const __half* __restrict__ ws,
                                                       float* __restrict__ out,
                                                       const GaussArgs ga)
{
    const int u   = blockIdx.x * 256 + threadIdx.x;  // 0 .. 2,408,447
    const int ch  = u / 3136;                        // 28 yt * 112 cg
    const int rem = u - ch * 3136;
    const int yt  = rem / 112;
    const int cg  = rem - yt * 112;
    const int y0  = yt * 8;
    const int x0  = cg * 2;

    const __half* col = ws  + (size_t)ch * PLANE + x0;
    float*        oc  = out + (size_t)ch * PLANE + x0;

    float a0[8], a1[8];
    #pragma unroll
    for (int j = 0; j < 8; ++j) { a0[j] = 0.f; a1[j] = 0.f; }

    // input rows yy = y0-16+i, i=0..38; row i feeds outputs j in
    // [max(0,i-31), min(7,i)] with weight wx[i-j] (k ascending == i ascending:
    // identical FMA order to prior rounds -> bit-identical output).
    #pragma unroll
    for (int i = 0; i < 39; ++i) {
        const int yy = y0 - 16 + i;
        float f0 = 0.f, f1 = 0.f;
        if (yy >= 0 && yy < SZW) {
            const __half2 h = *reinterpret_cast<const __half2*>(col + (size_t)yy * SZW);
            const float2 f = __half22float2(h);
            f0 = f.x; f1 = f.y;
        }
        const int jlo = (i - 31 > 0) ? (i - 31) : 0;
        const int jhi = (i < 7) ? i : 7;
        #pragma unroll
        for (int j = jlo; j <= jhi; ++j) {
            a0[j] = fmaf(ga.wx[i - j], f0, a0[j]);
            a1[j] = fmaf(ga.wx[i - j], f1, a1[j]);
        }
    }

    #pragma unroll
    for (int j = 0; j < 8; ++j)
        *reinterpret_cast<float2*>(oc + (size_t)(y0 + j) * SZW) =
            make_float2(a0[j], a1[j]);
}

extern "C" void kernel_launch(void* const* d_in, const int* in_sizes, int n_in,
                              void* d_out, int out_size, void* d_ws, size_t ws_size,
                              hipStream_t stream)
{
    const float* x  = (const float*)d_in[0];
    float*      out = (float*)d_out;
    __half*     ws  = (__half*)d_ws;  // 768*224*224*2 = 77,070,336 B

    // Host-computed Gaussian weights (double precision then rounded to f32 —
    // matches reference _gauss float64 path).
    GaussArgs ga;
    const double c0 = 1.0 / sqrt(2.0 * 3.14159265358979323846);
    for (int k = 0; k < 32; ++k) {
        double t = -1.0 + 2.0 * (double)k / 31.0;
        ga.wx[k] = (float)(c0 * exp(-t * t / 2.0));
    }
    ga.w31 = (float)c0;
    ga.w30 = (float)(c0 * exp(-0.5));

    dim3 g1(SZW, 6, 4);               // (y, phase*freqgroup, img)
    pass1_kernel<<<g1, 512, 0, stream>>>(x, ws, ga);
    // 768 ch * 28 yt * 112 cg = 2,408,448 threads = 9408 blocks of 256, exact
    pass2_kernel<<<9408, 256, 0, stream>>>(ws, out, ga);
}

// Round 13
// 116.720 us; speedup vs baseline: 1.4669x; 1.4669x over previous
//
#include <hip/hip_runtime.h>
#include <hip/hip_fp16.h>
#include <math.h>

// Normalization_60095182406123
//
// Separable 4D Gaussian filter of x^2 over axes (freq, orient, y, x):
//   out[c,y,x] = sum g3[df] g3[do] g32[dy] g32[dx] * xsq[c+(df-1)*16+(do-1)*2, y+dy-16, x+dx-16]
// c = img*192 + freq*16 + orient*2 + phase (same flat layout in and out).
//
// Pass 1 (unchanged since R8): x^2 + orient(3) + freq(3) + blur_x(32) -> ws (fp16), ~40 us
// Pass 2 (R13): blur_y(32) fp16->fp32 via LDS-staged y-tiles.
//   R8-R12 all read ws column-wise from global (448B stride, L2-missing, ~500cyc
//   L3 latency per 2-4B load) -> structurally latency-bound at ~95-117us.
//   Now: block = (ch, 56-row y-tile); stage 87 rows x 224 halves (39KB) into LDS
//   with coalesced uint4 row-major loads; compute reads columns from LDS
//   (conflict-free: 64 lanes span 32 banks, pair-broadcast). acc[14] static-only
//   (promotion lesson R9-R12: keep per-thread arrays <=16 floats, no shifts).
//
// ws needs 768*224*224*2 = 77,070,336 bytes of d_ws.

#define SZW   224
#define PLANE (224*224)
#define PW    256          // floats per LDS row in pass1: 16 zero | 224 | 15 zero | 1

struct GaussArgs {
    float wx[32];   // 32-tap Gaussian (l=32, w=1), matches reference _gauss
    float w30;      // 3-tap edge   = c*exp(-0.5)
    float w31;      // 3-tap center = c
};

// within-row float4-group swizzle (involution, preserves 8-group blocks)
__device__ __forceinline__ int swz(int g) { return g ^ ((g >> 3) & 7); }

__global__ __launch_bounds__(512, 6) void pass1_kernel(const float* __restrict__ in,
                                                       __half* __restrict__ ws,
                                                       const GaussArgs ga)
{
    __shared__ float s2[48 * PW];   // 49,152 B

    const int tid   = threadIdx.x;
    const int y     = blockIdx.x;          // 0..223
    const int by    = blockIdx.y;          // 0..5
    const int phase = by & 1;
    const int fg    = by >> 1;             // freq group: output f in [4fg, 4fg+4)
    const int img   = blockIdx.z;          // 0..3

    const float w31 = ga.w31;
    const float w30 = ga.w30;

    // ---- step 1: load x^2 (x-padded), orient 3-tap conv in regs, to LDS ----
    if (tid < 384) {
        const int lf  = tid >> 6;          // 0..5
        const int xp4 = tid & 63;
        const int f   = 4*fg - 1 + lf;     // -1..12
        const int gsw = swz(xp4);
        float4 a[8];
        if (f >= 0 && f < 12 && xp4 >= 4 && xp4 < 60) {
            const int x0 = xp4*4 - 16;     // 0..220, 16B-aligned
            const float* base = in + (size_t)(img*192 + f*16 + phase)*PLANE + y*SZW + x0;
            #pragma unroll
            for (int o = 0; o < 8; ++o) {
                float4 v = *reinterpret_cast<const float4*>(base + o*2*PLANE);
                a[o] = make_float4(v.x*v.x, v.y*v.y, v.z*v.z, v.w*v.w);
            }
        } else {
            #pragma unroll
            for (int o = 0; o < 8; ++o) a[o] = make_float4(0.f,0.f,0.f,0.f);
        }
        #pragma unroll
        for (int o = 0; o < 8; ++o) {
            float4 l = (o > 0) ? a[o-1] : make_float4(0.f,0.f,0.f,0.f);
            float4 r = (o < 7) ? a[o+1] : make_float4(0.f,0.f,0.f,0.f);
            float4 b;
            b.x = fmaf(w31, a[o].x, w30*(l.x + r.x));
            b.y = fmaf(w31, a[o].y, w30*(l.y + r.y));
            b.z = fmaf(w31, a[o].z, w30*(l.z + r.z));
            b.w = fmaf(w31, a[o].w, w30*(l.w + r.w));
            *reinterpret_cast<float4*>(&s2[(lf*8 + o)*PW + gsw*4]) = b;
        }
    }
    __syncthreads();

    // ---- step 2: freq 3-tap conv in place ----
    {
        const int o   = tid >> 6;          // 0..7
        const int xp4 = tid & 63;
        const int gsw = swz(xp4);
        float4 a[6];
        #pragma unroll
        for (int lf = 0; lf < 6; ++lf)
            a[lf] = *reinterpret_cast<const float4*>(&s2[(lf*8 + o)*PW + gsw*4]);
        #pragma unroll
        for (int lf = 1; lf < 5; ++lf) {
            float4 b;
            b.x = fmaf(w31, a[lf].x, w30*(a[lf-1].x + a[lf+1].x));
            b.y = fmaf(w31, a[lf].y, w30*(a[lf-1].y + a[lf+1].y));
            b.z = fmaf(w31, a[lf].z, w30*(a[lf-1].z + a[lf+1].z));
            b.w = fmaf(w31, a[lf].w, w30*(a[lf-1].w + a[lf+1].w));
            *reinterpret_cast<float4*>(&s2[(lf*8 + o)*PW + gsw*4]) = b;
        }
    }
    __syncthreads();

    // ---- step 3: 32-tap blur along x, 16 outputs/thread, fp16 store ----
    if (tid < 448) {
        const int r  = tid / 14;           // 0..31
        const int xg = tid - r*14;         // 0..13
        const int lf = 1 + (r >> 3);
        const int o  = r & 7;
        const int fo16 = (4*fg + (r >> 3))*16 + o*2;
        const int x0 = xg * 16;            // output x base (0..208)
        const int rowb = (lf*8 + o)*PW;
        const int g0 = 4*xg;

        float acc[16];
        #pragma unroll
        for (int j = 0; j < 16; ++j) acc[j] = 0.f;

        #pragma unroll
        for (int t = 0; t < 12; ++t) {
            const float4 q = *reinterpret_cast<const float4*>(
                &s2[rowb + swz(g0 + t)*4]);
            #pragma unroll
            for (int e = 0; e < 4; ++e) {
                const int m = 4*t + e;     // window float index 0..47
                const float qv = (e==0)?q.x:(e==1)?q.y:(e==2)?q.z:q.w;
                const int jlo = (m - 31 > 0) ? (m - 31) : 0;
                const int jhi = (m < 15) ? m : 15;
                #pragma unroll
                for (int j = jlo; j <= jhi; ++j)
                    acc[j] = fmaf(ga.wx[m - j], qv, acc[j]);
            }
        }

        union { uint4 u4[2]; __half2 h2[8]; } pk;
        #pragma unroll
        for (int s = 0; s < 8; ++s)
            pk.h2[s] = __floats2half2_rn(acc[2*s], acc[2*s+1]);

        __half* op = ws + (size_t)(img*192 + phase)*PLANE + (size_t)y*SZW
                        + (size_t)fo16*PLANE + x0;
        *reinterpret_cast<uint4*>(op)     = pk.u4[0];
        *reinterpret_cast<uint4*>(op + 8) = pk.u4[1];
    }
}

// Pass 2: y-blur via LDS-staged tiles. Grid (768 ch, 4 yt); block 256.
// Stage 87 rows (56 outputs + 31 halo) x 224 halves; compute per-column.
#define P2ROWS 88    // 87 used, rounded up
__global__ __launch_bounds__(256, 4) void pass2_kernel(const __half* __restrict__ ws,
                                                       float* __restrict__ out,
                                                       const GaussArgs ga)
{
    __shared__ __half tile[P2ROWS * SZW];   // 88*224*2 = 39,424 B

    const int tid = threadIdx.x;
    const int ch  = blockIdx.x;   // 0..767
    const int yb  = blockIdx.y * 56;

    const __half* wp = ws + (size_t)ch * PLANE;

    // ---- load: 87 rows x 28 uint4, coalesced; zero out-of-range rows ----
    for (int t = tid; t < 87*28; t += 256) {
        const int r = t / 28;
        const int g = t - r*28;
        const int yy = yb - 16 + r;
        uint4 v = make_uint4(0u, 0u, 0u, 0u);
        if (yy >= 0 && yy < SZW)
            v = *reinterpret_cast<const uint4*>(wp + (size_t)yy * SZW + g*8);
        *reinterpret_cast<uint4*>(&tile[r*SZW + g*8]) = v;
    }
    __syncthreads();

    // ---- compute: thread = column; 4 chunks of 14 outputs ----
    if (tid < SZW) {
        const int x = tid;
        float* oc = out + (size_t)ch * PLANE + x;

        #pragma unroll 1
        for (int c = 0; c < 4; ++c) {
            const int sbase = c * 14;      // stage row of first input for chunk

            float acc[14];
            #pragma unroll
            for (int j = 0; j < 14; ++j) acc[j] = 0.f;

            // input stage rows sbase+i, i=0..44; row i feeds outputs
            // j in [max(0,i-31), min(13,i)] with weight wx[i-j]
            // (k = i-j ascending per output: identical FMA order -> bit-identical)
            #pragma unroll
            for (int i = 0; i < 45; ++i) {
                const float r = __half2float(tile[(sbase + i)*SZW + x]);
                const int jlo = (i - 31 > 0) ? (i - 31) : 0;
                const int jhi = (i < 13) ? i : 13;
                #pragma unroll
                for (int j = jlo; j <= jhi; ++j)
                    acc[j] = fmaf(ga.wx[i - j], r, acc[j]);
            }

            #pragma unroll
            for (int j = 0; j < 14; ++j)
                oc[(size_t)(yb + c*14 + j) * SZW] = acc[j];
        }
    }
}

extern "C" void kernel_launch(void* const* d_in, const int* in_sizes, int n_in,
                              void* d_out, int out_size, void* d_ws, size_t ws_size,
                              hipStream_t stream)
{
    const float* x  = (const float*)d_in[0];
    float*      out = (float*)d_out;
    __half*     ws  = (__half*)d_ws;  // 768*224*224*2 = 77,070,336 B

    // Host-computed Gaussian weights (double precision then rounded to f32 —
    // matches reference _gauss float64 path).
    GaussArgs ga;
    const double c0 = 1.0 / sqrt(2.0 * 3.14159265358979323846);
    for (int k = 0; k < 32; ++k) {
        double t = -1.0 + 2.0 * (double)k / 31.0;
        ga.wx[k] = (float)(c0 * exp(-t * t / 2.0));
    }
    ga.w31 = (float)c0;
    ga.w30 = (float)(c0 * exp(-0.5));

    dim3 g1(SZW, 6, 4);               // (y, phase*freqgroup, img)
    pass1_kernel<<<g1, 512, 0, stream>>>(x, ws, ga);
    dim3 g2(768, 4);                  // (channel, y-tile)
    pass2_kernel<<<g2, 256, 0, stream>>>(ws, out, ga);
}

// Round 14
// 113.927 us; speedup vs baseline: 1.5029x; 1.0245x over previous
//
#include <hip/hip_runtime.h>
#include <hip/hip_fp16.h>
#include <math.h>

// Normalization_60095182406123
//
// Separable 4D Gaussian filter of x^2 over axes (freq, orient, y, x):
//   out[c,y,x] = sum g3[df] g3[do] g32[dy] g32[dx] * xsq[c+(df-1)*16+(do-1)*2, y+dy-16, x+dx-16]
// c = img*192 + freq*16 + orient*2 + phase (same flat layout in and out).
//
// Pass 1 (unchanged since R8): x^2 + orient(3) + freq(3) + blur_x(32) -> ws (fp16), ~40 us
// Pass 2 (R14): blur_y(32) fp16->fp32, LDS-staged 112-row y-tiles (halo amp 1.28),
//   half2 column-pair reads (ds_read_b32: 2 cols/instr), acc as a0[14],a1[14]
//   (<=14 elements/array — the proven register-promotable shape; R11's acc[28]
//   failed promotion, R12's a0[8]/a1[8] and R13's acc[14] promoted).
//
// ws needs 768*224*224*2 = 77,070,336 bytes of d_ws.

#define SZW   224
#define PLANE (224*224)
#define PW    256          // floats per LDS row in pass1: 16 zero | 224 | 15 zero | 1

struct GaussArgs {
    float wx[32];   // 32-tap Gaussian (l=32, w=1), matches reference _gauss
    float w30;      // 3-tap edge   = c*exp(-0.5)
    float w31;      // 3-tap center = c
};

// within-row float4-group swizzle (involution, preserves 8-group blocks)
__device__ __forceinline__ int swz(int g) { return g ^ ((g >> 3) & 7); }

__global__ __launch_bounds__(512, 6) void pass1_kernel(const float* __restrict__ in,
                                                       __half* __restrict__ ws,
                                                       const GaussArgs ga)
{
    __shared__ float s2[48 * PW];   // 49,152 B

    const int tid   = threadIdx.x;
    const int y     = blockIdx.x;          // 0..223
    const int by    = blockIdx.y;          // 0..5
    const int phase = by & 1;
    const int fg    = by >> 1;             // freq group: output f in [4fg, 4fg+4)
    const int img   = blockIdx.z;          // 0..3

    const float w31 = ga.w31;
    const float w30 = ga.w30;

    // ---- step 1: load x^2 (x-padded), orient 3-tap conv in regs, to LDS ----
    if (tid < 384) {
        const int lf  = tid >> 6;          // 0..5
        const int xp4 = tid & 63;
        const int f   = 4*fg - 1 + lf;     // -1..12
        const int gsw = swz(xp4);
        float4 a[8];
        if (f >= 0 && f < 12 && xp4 >= 4 && xp4 < 60) {
            const int x0 = xp4*4 - 16;     // 0..220, 16B-aligned
            const float* base = in + (size_t)(img*192 + f*16 + phase)*PLANE + y*SZW + x0;
            #pragma unroll
            for (int o = 0; o < 8; ++o) {
                float4 v = *reinterpret_cast<const float4*>(base + o*2*PLANE);
                a[o] = make_float4(v.x*v.x, v.y*v.y, v.z*v.z, v.w*v.w);
            }
        } else {
            #pragma unroll
            for (int o = 0; o < 8; ++o) a[o] = make_float4(0.f,0.f,0.f,0.f);
        }
        #pragma unroll
        for (int o = 0; o < 8; ++o) {
            float4 l = (o > 0) ? a[o-1] : make_float4(0.f,0.f,0.f,0.f);
            float4 r = (o < 7) ? a[o+1] : make_float4(0.f,0.f,0.f,0.f);
            float4 b;
            b.x = fmaf(w31, a[o].x, w30*(l.x + r.x));
            b.y = fmaf(w31, a[o].y, w30*(l.y + r.y));
            b.z = fmaf(w31, a[o].z, w30*(l.z + r.z));
            b.w = fmaf(w31, a[o].w, w30*(l.w + r.w));
            *reinterpret_cast<float4*>(&s2[(lf*8 + o)*PW + gsw*4]) = b;
        }
    }
    __syncthreads();

    // ---- step 2: freq 3-tap conv in place ----
    {
        const int o   = tid >> 6;          // 0..7
        const int xp4 = tid & 63;
        const int gsw = swz(xp4);
        float4 a[6];
        #pragma unroll
        for (int lf = 0; lf < 6; ++lf)
            a[lf] = *reinterpret_cast<const float4*>(&s2[(lf*8 + o)*PW + gsw*4]);
        #pragma unroll
        for (int lf = 1; lf < 5; ++lf) {
            float4 b;
            b.x = fmaf(w31, a[lf].x, w30*(a[lf-1].x + a[lf+1].x));
            b.y = fmaf(w31, a[lf].y, w30*(a[lf-1].y + a[lf+1].y));
            b.z = fmaf(w31, a[lf].z, w30*(a[lf-1].z + a[lf+1].z));
            b.w = fmaf(w31, a[lf].w, w30*(a[lf-1].w + a[lf+1].w));
            *reinterpret_cast<float4*>(&s2[(lf*8 + o)*PW + gsw*4]) = b;
        }
    }
    __syncthreads();

    // ---- step 3: 32-tap blur along x, 16 outputs/thread, fp16 store ----
    if (tid < 448) {
        const int r  = tid / 14;           // 0..31
        const int xg = tid - r*14;         // 0..13
        const int lf = 1 + (r >> 3);
        const int o  = r & 7;
        const int fo16 = (4*fg + (r >> 3))*16 + o*2;
        const int x0 = xg * 16;            // output x base (0..208)
        const int rowb = (lf*8 + o)*PW;
        const int g0 = 4*xg;

        float acc[16];
        #pragma unroll
        for (int j = 0; j < 16; ++j) acc[j] = 0.f;

        #pragma unroll
        for (int t = 0; t < 12; ++t) {
            const float4 q = *reinterpret_cast<const float4*>(
                &s2[rowb + swz(g0 + t)*4]);
            #pragma unroll
            for (int e = 0; e < 4; ++e) {
                const int m = 4*t + e;     // window float index 0..47
                const float qv = (e==0)?q.x:(e==1)?q.y:(e==2)?q.z:q.w;
                const int jlo = (m - 31 > 0) ? (m - 31) : 0;
                const int jhi = (m < 15) ? m : 15;
                #pragma unroll
                for (int j = jlo; j <= jhi; ++j)
                    acc[j] = fmaf(ga.wx[m - j], qv, acc[j]);
            }
        }

        union { uint4 u4[2]; __half2 h2[8]; } pk;
        #pragma unroll
        for (int s = 0; s < 8; ++s)
            pk.h2[s] = __floats2half2_rn(acc[2*s], acc[2*s+1]);

        __half* op = ws + (size_t)(img*192 + phase)*PLANE + (size_t)y*SZW
                        + (size_t)fo16*PLANE + x0;
        *reinterpret_cast<uint4*>(op)     = pk.u4[0];
        *reinterpret_cast<uint4*>(op + 8) = pk.u4[1];
    }
}

// Pass 2: y-blur via LDS-staged 112-row tiles. Grid (768 ch, 2 yt); block 256.
// Stage 143 rows (112 outputs + 31 halo) x 224 halves = 64,064 B.
// Compute: thread = (col-pair 0..111, chunk-half 0..1); 4 chunks of 14 outputs,
// half2 LDS reads serve both columns.
#define P2R 143
__global__ __launch_bounds__(256, 4) void pass2_kernel(const __half* __restrict__ ws,
                                                       float* __restrict__ out,
                                                       const GaussArgs ga)
{
    __shared__ __half tile[P2R * SZW];   // 64,064 B

    const int tid = threadIdx.x;
    const int ch  = blockIdx.x;   // 0..767
    const int yb  = blockIdx.y * 112;

    const __half* wp = ws + (size_t)ch * PLANE;

    // ---- load: 143 rows x 28 uint4, coalesced; zero out-of-range rows ----
    for (int t = tid; t < P2R*28; t += 256) {
        const int r = t / 28;
        const int g = t - r*28;
        const int yy = yb - 16 + r;
        uint4 v = make_uint4(0u, 0u, 0u, 0u);
        if (yy >= 0 && yy < SZW)
            v = *reinterpret_cast<const uint4*>(wp + (size_t)yy * SZW + g*8);
        *reinterpret_cast<uint4*>(&tile[r*SZW + g*8]) = v;
    }
    __syncthreads();

    // ---- compute: 224 threads = 112 col-pairs x 2 chunk-halves ----
    if (tid < 224) {
        const int cp    = tid % 112;       // column pair -> cols 2cp, 2cp+1
        const int chalf = tid / 112;       // chunks {4*chalf .. 4*chalf+3}
        const int x0    = cp * 2;

        float* oc = out + (size_t)ch * PLANE + x0;

        #pragma unroll 1
        for (int g = 0; g < 4; ++g) {
            const int cc    = chalf*4 + g; // chunk 0..7
            const int sbase = cc * 14;     // stage row of first input

            float a0[14], a1[14];
            #pragma unroll
            for (int j = 0; j < 14; ++j) { a0[j] = 0.f; a1[j] = 0.f; }

            // stage rows sbase+i, i=0..44; row i feeds outputs j in
            // [max(0,i-31), min(13,i)] with weight wx[i-j]
            // (k ascending per output -> identical FMA order, bit-identical)
            #pragma unroll
            for (int i = 0; i < 45; ++i) {
                const __half2 h = *reinterpret_cast<const __half2*>(
                    &tile[(sbase + i)*SZW + x0]);
                const float2 f = __half22float2(h);
                const int jlo = (i - 31 > 0) ? (i - 31) : 0;
                const int jhi = (i < 13) ? i : 13;
                #pragma unroll
                for (int j = jlo; j <= jhi; ++j) {
                    a0[j] = fmaf(ga.wx[i - j], f.x, a0[j]);
                    a1[j] = fmaf(ga.wx[i - j], f.y, a1[j]);
                }
            }

            #pragma unroll
            for (int j = 0; j < 14; ++j)
                *reinterpret_cast<float2*>(
                    oc + (size_t)(yb + cc*14 + j) * SZW) = make_float2(a0[j], a1[j]);
        }
    }
}

extern "C" void kernel_launch(void* const* d_in, const int* in_sizes, int n_in,
                              void* d_out, int out_size, void* d_ws, size_t ws_size,
                              hipStream_t stream)
{
    const float* x  = (const float*)d_in[0];
    float*      out = (float*)d_out;
    __half*     ws  = (__half*)d_ws;  // 768*224*224*2 = 77,070,336 B

    // Host-computed Gaussian weights (double precision then rounded to f32 —
    // matches reference _gauss float64 path).
    GaussArgs ga;
    const double c0 = 1.0 / sqrt(2.0 * 3.14159265358979323846);
    for (int k = 0; k < 32; ++k) {
        double t = -1.0 + 2.0 * (double)k / 31.0;
        ga.wx[k] = (float)(c0 * exp(-t * t / 2.0));
    }
    ga.w31 = (float)c0;
    ga.w30 = (float)(c0 * exp(-0.5));

    dim3 g1(SZW, 6, 4);               // (y, phase*freqgroup, img)
    pass1_kernel<<<g1, 512, 0, stream>>>(x, ws, ga);
    dim3 g2(768, 2);                  // (channel, y-tile)
    pass2_kernel<<<g2, 256, 0, stream>>>(ws, out, ga);
}

// Round 15
// 109.715 us; speedup vs baseline: 1.5606x; 1.0384x over previous
//
#include <hip/hip_runtime.h>
#include <hip/hip_fp16.h>
#include <math.h>

// Normalization_60095182406123
//
// Separable 4D Gaussian filter of x^2 over axes (freq, orient, y, x):
//   out[c,y,x] = sum g3[df] g3[do] g32[dy] g32[dx] * xsq[c+(df-1)*16+(do-1)*2, y+dy-16, x+dx-16]
// c = img*192 + freq*16 + orient*2 + phase (same flat layout in and out).
//
// Pass 1 (unchanged since R8): x^2 + orient(3) + freq(3) + blur_x(32) -> ws (fp16), ~40 us
// Pass 2 (R15): blur_y(32) fp16->fp32, LDS-staged 143-row tile, 512-thread block.
//   R14 (256 thr, 2 blocks/CU) = 8 waves/CU -> stage/compute/store phases
//   serialized. 512 threads -> 16 waves/CU; compute = 112 col-pairs x 4 groups
//   x 2 chunks of 14. acc arrays <=14 elems (promotion lesson R9-R12).
//
// ws needs 768*224*224*2 = 77,070,336 bytes of d_ws.

#define SZW   224
#define PLANE (224*224)
#define PW    256          // floats per LDS row in pass1: 16 zero | 224 | 15 zero | 1

struct GaussArgs {
    float wx[32];   // 32-tap Gaussian (l=32, w=1), matches reference _gauss
    float w30;      // 3-tap edge   = c*exp(-0.5)
    float w31;      // 3-tap center = c
};

// within-row float4-group swizzle (involution, preserves 8-group blocks)
__device__ __forceinline__ int swz(int g) { return g ^ ((g >> 3) & 7); }

__global__ __launch_bounds__(512, 6) void pass1_kernel(const float* __restrict__ in,
                                                       __half* __restrict__ ws,
                                                       const GaussArgs ga)
{
    __shared__ float s2[48 * PW];   // 49,152 B

    const int tid   = threadIdx.x;
    const int y     = blockIdx.x;          // 0..223
    const int by    = blockIdx.y;          // 0..5
    const int phase = by & 1;
    const int fg    = by >> 1;             // freq group: output f in [4fg, 4fg+4)
    const int img   = blockIdx.z;          // 0..3

    const float w31 = ga.w31;
    const float w30 = ga.w30;

    // ---- step 1: load x^2 (x-padded), orient 3-tap conv in regs, to LDS ----
    if (tid < 384) {
        const int lf  = tid >> 6;          // 0..5
        const int xp4 = tid & 63;
        const int f   = 4*fg - 1 + lf;     // -1..12
        const int gsw = swz(xp4);
        float4 a[8];
        if (f >= 0 && f < 12 && xp4 >= 4 && xp4 < 60) {
            const int x0 = xp4*4 - 16;     // 0..220, 16B-aligned
            const float* base = in + (size_t)(img*192 + f*16 + phase)*PLANE + y*SZW + x0;
            #pragma unroll
            for (int o = 0; o < 8; ++o) {
                float4 v = *reinterpret_cast<const float4*>(base + o*2*PLANE);
                a[o] = make_float4(v.x*v.x, v.y*v.y, v.z*v.z, v.w*v.w);
            }
        } else {
            #pragma unroll
            for (int o = 0; o < 8; ++o) a[o] = make_float4(0.f,0.f,0.f,0.f);
        }
        #pragma unroll
        for (int o = 0; o < 8; ++o) {
            float4 l = (o > 0) ? a[o-1] : make_float4(0.f,0.f,0.f,0.f);
            float4 r = (o < 7) ? a[o+1] : make_float4(0.f,0.f,0.f,0.f);
            float4 b;
            b.x = fmaf(w31, a[o].x, w30*(l.x + r.x));
            b.y = fmaf(w31, a[o].y, w30*(l.y + r.y));
            b.z = fmaf(w31, a[o].z, w30*(l.z + r.z));
            b.w = fmaf(w31, a[o].w, w30*(l.w + r.w));
            *reinterpret_cast<float4*>(&s2[(lf*8 + o)*PW + gsw*4]) = b;
        }
    }
    __syncthreads();

    // ---- step 2: freq 3-tap conv in place ----
    {
        const int o   = tid >> 6;          // 0..7
        const int xp4 = tid & 63;
        const int gsw = swz(xp4);
        float4 a[6];
        #pragma unroll
        for (int lf = 0; lf < 6; ++lf)
            a[lf] = *reinterpret_cast<const float4*>(&s2[(lf*8 + o)*PW + gsw*4]);
        #pragma unroll
        for (int lf = 1; lf < 5; ++lf) {
            float4 b;
            b.x = fmaf(w31, a[lf].x, w30*(a[lf-1].x + a[lf+1].x));
            b.y = fmaf(w31, a[lf].y, w30*(a[lf-1].y + a[lf+1].y));
            b.z = fmaf(w31, a[lf].z, w30*(a[lf-1].z + a[lf+1].z));
            b.w = fmaf(w31, a[lf].w, w30*(a[lf-1].w + a[lf+1].w));
            *reinterpret_cast<float4*>(&s2[(lf*8 + o)*PW + gsw*4]) = b;
        }
    }
    __syncthreads();

    // ---- step 3: 32-tap blur along x, 16 outputs/thread, fp16 store ----
    if (tid < 448) {
        const int r  = tid / 14;           // 0..31
        const int xg = tid - r*14;         // 0..13
        const int lf = 1 + (r >> 3);
        const int o  = r & 7;
        const int fo16 = (4*fg + (r >> 3))*16 + o*2;
        const int x0 = xg * 16;            // output x base (0..208)
        const int rowb = (lf*8 + o)*PW;
        const int g0 = 4*xg;

        float acc[16];
        #pragma unroll
        for (int j = 0; j < 16; ++j) acc[j] = 0.f;

        #pragma unroll
        for (int t = 0; t < 12; ++t) {
            const float4 q = *reinterpret_cast<const float4*>(
                &s2[rowb + swz(g0 + t)*4]);
            #pragma unroll
            for (int e = 0; e < 4; ++e) {
                const int m = 4*t + e;     // window float index 0..47
                const float qv = (e==0)?q.x:(e==1)?q.y:(e==2)?q.z:q.w;
                const int jlo = (m - 31 > 0) ? (m - 31) : 0;
                const int jhi = (m < 15) ? m : 15;
                #pragma unroll
                for (int j = jlo; j <= jhi; ++j)
                    acc[j] = fmaf(ga.wx[m - j], qv, acc[j]);
            }
        }

        union { uint4 u4[2]; __half2 h2[8]; } pk;
        #pragma unroll
        for (int s = 0; s < 8; ++s)
            pk.h2[s] = __floats2half2_rn(acc[2*s], acc[2*s+1]);

        __half* op = ws + (size_t)(img*192 + phase)*PLANE + (size_t)y*SZW
                        + (size_t)fo16*PLANE + x0;
        *reinterpret_cast<uint4*>(op)     = pk.u4[0];
        *reinterpret_cast<uint4*>(op + 8) = pk.u4[1];
    }
}

// Pass 2: y-blur via LDS-staged 143-row tile (112 outputs + 31 halo), 512 threads.
// Stage: 143 x 28 uint4, all 512 lanes. Compute: 448 threads = 112 col-pairs x
// 4 groups; each does 2 chunks of 14 outputs with half2 LDS reads.
#define P2R 143
__global__ __launch_bounds__(512, 4) void pass2_kernel(const __half* __restrict__ ws,
                                                       float* __restrict__ out,
                                                       const GaussArgs ga)
{
    __shared__ __half tile[P2R * SZW];   // 64,064 B

    const int tid = threadIdx.x;
    const int ch  = blockIdx.x;   // 0..767
    const int yb  = blockIdx.y * 112;

    const __half* wp = ws + (size_t)ch * PLANE;

    // ---- load: 143 rows x 28 uint4, coalesced; zero out-of-range rows ----
    for (int t = tid; t < P2R*28; t += 512) {
        const int r = t / 28;
        const int g = t - r*28;
        const int yy = yb - 16 + r;
        uint4 v = make_uint4(0u, 0u, 0u, 0u);
        if (yy >= 0 && yy < SZW)
            v = *reinterpret_cast<const uint4*>(wp + (size_t)yy * SZW + g*8);
        *reinterpret_cast<uint4*>(&tile[r*SZW + g*8]) = v;
    }
    __syncthreads();

    // ---- compute: 448 threads = 112 col-pairs x 4 groups of 2 chunks ----
    if (tid < 448) {
        const int cp = tid % 112;          // column pair -> cols 2cp, 2cp+1
        const int gq = tid / 112;          // 0..3 -> chunks {2gq, 2gq+1}
        const int x0 = cp * 2;

        float* oc = out + (size_t)ch * PLANE + x0;

        #pragma unroll 1
        for (int s = 0; s < 2; ++s) {
            const int cc    = gq*2 + s;    // chunk 0..7
            const int sbase = cc * 14;     // stage row of first input

            float a0[14], a1[14];
            #pragma unroll
            for (int j = 0; j < 14; ++j) { a0[j] = 0.f; a1[j] = 0.f; }

            // stage rows sbase+i, i=0..44; row i feeds outputs j in
            // [max(0,i-31), min(13,i)] with weight wx[i-j]
            // (k ascending per output -> identical FMA order, bit-identical)
            #pragma unroll
            for (int i = 0; i < 45; ++i) {
                const __half2 h = *reinterpret_cast<const __half2*>(
                    &tile[(sbase + i)*SZW + x0]);
                const float2 f = __half22float2(h);
                const int jlo = (i - 31 > 0) ? (i - 31) : 0;
                const int jhi = (i < 13) ? i : 13;
                #pragma unroll
                for (int j = jlo; j <= jhi; ++j) {
                    a0[j] = fmaf(ga.wx[i - j], f.x, a0[j]);
                    a1[j] = fmaf(ga.wx[i - j], f.y, a1[j]);
                }
            }

            #pragma unroll
            for (int j = 0; j < 14; ++j)
                *reinterpret_cast<float2*>(
                    oc + (size_t)(yb + cc*14 + j) * SZW) = make_float2(a0[j], a1[j]);
        }
    }
}

extern "C" void kernel_launch(void* const* d_in, const int* in_sizes, int n_in,
                              void* d_out, int out_size, void* d_ws, size_t ws_size,
                              hipStream_t stream)
{
    const float* x  = (const float*)d_in[0];
    float*      out = (float*)d_out;
    __half*     ws  = (__half*)d_ws;  // 768*224*224*2 = 77,070,336 B

    // Host-computed Gaussian weights (double precision then rounded to f32 —
    // matches reference _gauss float64 path).
    GaussArgs ga;
    const double c0 = 1.0 / sqrt(2.0 * 3.14159265358979323846);
    for (int k = 0; k < 32; ++k) {
        double t = -1.0 + 2.0 * (double)k / 31.0;
        ga.wx[k] = (float)(c0 * exp(-t * t / 2.0));
    }
    ga.w31 = (float)c0;
    ga.w30 = (float)(c0 * exp(-0.5));

    dim3 g1(SZW, 6, 4);               // (y, phase*freqgroup, img)
    pass1_kernel<<<g1, 512, 0, stream>>>(x, ws, ga);
    dim3 g2(768, 2);                  // (channel, y-tile)
    pass2_kernel<<<g2, 512, 0, stream>>>(ws, out, ga);
}